// Round 3
// baseline (682.501 us; speedup 1.0000x reference)
//
#include <hip/hip_runtime.h>
#include <stdint.h>

#define B_ 2
#define S_ 2048
#define H_ 16
#define D_ 64
#define BS_ 128
#define NB_ 16
#define R_ 64

typedef __bf16 bf16x8 __attribute__((ext_vector_type(8)));
typedef __bf16 bf16x4 __attribute__((ext_vector_type(4)));
typedef float  f32x4  __attribute__((ext_vector_type(4)));

// One block per (b, n, h, half): 64 q-rows x 128 k-cols of the block-diagonal
// attention. 4 waves x 16 q-rows. grid.x = 1024; grid.y = 5 replicates the
// identical (pure-overwrite, idempotent) work for timing calibration:
// dur = tax + 5*T  ->  T ~= (dur - dur_round2)/4.
// LDS 33KB: k_lds[128][64]bf16 (QK) overlaid by p_lds[64][128]bf16 (PV);
// vt_lds[64][128]bf16; cnt[64] int. Swizzle byte^=(row&7)<<4: verified to give
// the uniform 8-lanes-per-16B-slot optimum for wave64 ds_read_b128.
// Mask tile is loaded directly into the MFMA C-init (acc = mask), and Q is
// pre-scaled by 0.125 (exact pow2) at bf16 conversion -> softmax reads acc raw.
// Global-attn part == out[:, :G] += v[:, :G]; random part == out[:, ridx] +=
// mult * v[ridx] (softmax rows sum to 1) -> both fused into the epilogue.
__global__ __launch_bounds__(256, 4) void bb_diag(
    const float* __restrict__ q, const float* __restrict__ k,
    const float* __restrict__ v, const float* __restrict__ mask,
    const int* __restrict__ ridx, float* __restrict__ out)
{
    __shared__ __align__(16) uint8_t smem[33024];
    uint8_t* const k_lds  = smem;          // 16KB, QK phase
    uint8_t* const p_lds  = smem;          // 16KB, PV phase (overlays k_lds)
    uint8_t* const vt_lds = smem + 16384;  // 16KB
    int* const cnt = (int*)(smem + 32768); // 64 ints

    const int tid  = (int)threadIdx.x;
    const int w    = tid >> 6;     // wave 0..3
    const int lane = tid & 63;
    const int g    = lane >> 4;    // lane group 0..3
    const int c    = lane & 15;

    const int blk  = (int)blockIdx.x;   // replica index blockIdx.y is ignored
    const int half = blk >> 9;
    const int rest = blk & 511;
    const int h = rest & 15;
    const int n = (rest >> 4) & 15;
    const int b = rest >> 8;

    const int RS = H_ * D_;  // 1024 floats between consecutive seq rows
    const size_t base = ((size_t)((b * S_ + n * BS_) * H_ + h)) * D_;
    const float* __restrict__ qg = q + base;
    const float* __restrict__ kg = k + base;
    const float* __restrict__ vg = v + base;
    float* __restrict__ og = out + base;

    if (tid < 64) cnt[tid] = 0;

    // ---- stage K (row-major bf16) and V^T (d-major bf16), swizzled ----
    #pragma unroll
    for (int it = 0; it < 8; ++it) {
        int i   = it * 256 + tid;    // 2048 f32x4 tiles of 128x64
        int row = i >> 4;
        int c4  = i & 15;
        f32x4 kv = *(const f32x4*)(kg + (size_t)row * RS + c4 * 4);
        bf16x4 kb;
        kb[0] = (__bf16)kv[0]; kb[1] = (__bf16)kv[1];
        kb[2] = (__bf16)kv[2]; kb[3] = (__bf16)kv[3];
        uint32_t ka = ((uint32_t)(row * 128 + c4 * 8)) ^ ((row & 7) << 4);
        *(bf16x4*)(k_lds + ka) = kb;

        f32x4 vv = *(const f32x4*)(vg + (size_t)row * RS + c4 * 4);
        #pragma unroll
        for (int jj = 0; jj < 4; ++jj) {
            int j = (jj + c4) & 3;   // rotate to spread write banks
            int d = c4 * 4 + j;
            uint32_t va = ((uint32_t)(d * 256 + row * 2)) ^ ((d & 7) << 4);
            float vf = (j == 0) ? vv[0] : (j == 1) ? vv[1] : (j == 2) ? vv[2] : vv[3];
            *(__bf16*)(vt_lds + va) = (__bf16)vf;
        }
    }

    // ---- prefetch Q fragments, pre-scaled by SCALE=0.125 (exact pow2) ----
    bf16x8 qf[2];
    {
        int row_l = w * 16 + c;
        const float* qrow = qg + (size_t)(half * 64 + row_l) * RS;
        #pragma unroll
        for (int ks = 0; ks < 2; ++ks) {
            f32x4 x0 = *(const f32x4*)(qrow + ks * 32 + g * 8);
            f32x4 x1 = *(const f32x4*)(qrow + ks * 32 + g * 8 + 4);
            union { bf16x8 v8; __bf16 e[8]; } cv;
            #pragma unroll
            for (int j = 0; j < 4; ++j) {
                cv.e[j]     = (__bf16)(0.125f * x0[j]);
                cv.e[4 + j] = (__bf16)(0.125f * x1[j]);
            }
            qf[ks] = cv.v8;
        }
    }

    // ---- mask tile -> MFMA C-init (loads overlap the staging latency) ----
    f32x4 acc[8];
    {
        const float* mb = mask + ((size_t)(b * H_ + h) * S_ + n * BS_ + half * 64 + w * 16) * S_
                               + (size_t)(n * BS_);
        #pragma unroll
        for (int j = 0; j < 4; ++j) {
            const float* mrow = mb + (size_t)(g * 4 + j) * S_;
            #pragma unroll
            for (int nt = 0; nt < 8; ++nt) acc[nt][j] = mrow[nt * 16 + c];
        }
    }
    __syncthreads();

    // rand-index multiplicities for this block's 64 rows
    if (tid < 64) {
        int s = ridx[tid];
        int lo = n * BS_ + half * 64;
        if (s >= lo && s < lo + 64) atomicAdd(&cnt[s - lo], 1);
    }

    // ---- QK^T: scores[16 rows][128 cols] per wave, acc starts as mask ----
    #pragma unroll
    for (int ks = 0; ks < 2; ++ks) {
        #pragma unroll
        for (int nt = 0; nt < 8; ++nt) {
            int krow = nt * 16 + c;
            uint32_t ka = ((uint32_t)(krow * 128 + ks * 64 + g * 16)) ^ ((krow & 7) << 4);
            bf16x8 bfr = *(const bf16x8*)(k_lds + ka);
            acc[nt] = __builtin_amdgcn_mfma_f32_16x16x32_bf16(qf[ks], bfr, acc[nt], 0, 0, 0);
        }
    }
    __syncthreads();  // K-LDS reads complete before P overlays the region

    // ---- softmax (row in registers), write P (bf16) ----
    float rcp_s[4];
    #pragma unroll
    for (int j = 0; j < 4; ++j) {
        int row = w * 16 + g * 4 + j;   // local q-row 0..63 (D-layout)
        float mx = -1e30f;
        #pragma unroll
        for (int nt = 0; nt < 8; ++nt) mx = fmaxf(mx, acc[nt][j]);
        #pragma unroll
        for (int t = 1; t < 16; t <<= 1) mx = fmaxf(mx, __shfl_xor(mx, t));
        float sum = 0.f;
        #pragma unroll
        for (int nt = 0; nt < 8; ++nt) {
            float p = __expf(acc[nt][j] - mx);
            sum += p;
            uint32_t pa = ((uint32_t)(row * 256 + (nt * 16 + c) * 2)) ^ ((row & 7) << 4);
            *(__bf16*)(p_lds + pa) = (__bf16)p;
        }
        #pragma unroll
        for (int t = 1; t < 16; t <<= 1) sum += __shfl_xor(sum, t);
        rcp_s[j] = 1.0f / sum;
    }
    __syncthreads();

    // ---- PV: out[16 rows][64 d] per wave ----
    f32x4 acc2[4];
    #pragma unroll
    for (int nt = 0; nt < 4; ++nt) acc2[nt] = f32x4{0.f, 0.f, 0.f, 0.f};
    #pragma unroll
    for (int kk = 0; kk < 4; ++kk) {
        int prow = w * 16 + c;
        uint32_t pa = ((uint32_t)(prow * 256 + kk * 64 + g * 16)) ^ ((prow & 7) << 4);
        bf16x8 af = *(const bf16x8*)(p_lds + pa);
        #pragma unroll
        for (int nt = 0; nt < 4; ++nt) {
            int drow = nt * 16 + c;
            uint32_t va = ((uint32_t)(drow * 256 + kk * 64 + g * 16)) ^ ((drow & 7) << 4);
            bf16x8 bfr = *(const bf16x8*)(vt_lds + va);
            acc2[nt] = __builtin_amdgcn_mfma_f32_16x16x32_bf16(af, bfr, acc2[nt], 0, 0, 0);
        }
    }

    // ---- epilogue: normalize; fuse global-attn (+v, n==0) and rand (+mult*v)
    #pragma unroll
    for (int j = 0; j < 4; ++j) {
        int r_l = w * 16 + g * 4 + j;      // local row 0..63
        int r_t = half * 64 + r_l;         // row within the 128-row tile
        float rc = rcp_s[j];
        float coef = (float)(cnt[r_l] + ((n == 0) ? 1 : 0));
        #pragma unroll
        for (int nt = 0; nt < 4; ++nt) {
            int col = nt * 16 + c;
            float val = acc2[nt][j] * rc;
            if (coef != 0.f) val += coef * vg[(size_t)r_t * RS + col];
            og[(size_t)r_t * RS + col] = val;
        }
    }
}

extern "C" void kernel_launch(void* const* d_in, const int* in_sizes, int n_in,
                              void* d_out, int out_size, void* d_ws, size_t ws_size,
                              hipStream_t stream) {
    const float* q    = (const float*)d_in[0];
    const float* k    = (const float*)d_in[1];
    const float* v    = (const float*)d_in[2];
    const float* mask = (const float*)d_in[3];
    const int*   ridx = (const int*)d_in[4];
    float* out = (float*)d_out;

    // grid.y = 5: identical idempotent replicas for timing calibration.
    bb_diag<<<dim3(B_ * NB_ * H_ * 2, 5), dim3(256), 0, stream>>>(q, k, v, mask, ridx, out);
}

// Round 7
// 616.540 us; speedup vs baseline: 1.1070x; 1.1070x over previous
//
#include <hip/hip_runtime.h>
#include <stdint.h>

#define B_ 2
#define S_ 2048
#define H_ 16
#define D_ 64
#define BS_ 128
#define NB_ 16
#define R_ 64

typedef __bf16 bf16x8 __attribute__((ext_vector_type(8)));
typedef __bf16 bf16x4 __attribute__((ext_vector_type(4)));
typedef float  f32x4  __attribute__((ext_vector_type(4)));

// One block per (b, n, h, half): 64 q-rows x 128 k-cols of the block-diagonal
// attention. 4 waves x 16 q-rows. Grid = 1024 -> 4 blocks/CU (16 waves/CU).
//
// Calibration (round 3, grid.y=5 replication): T_kernel ~= 17.3 us steady;
// mandatory traffic 134 MB (~21 us HBM floor, partially LLC-resident), so the
// kernel is at the memory roofline. dur_us is dominated by ~596 us of harness
// reset tax (2 GiB ws poison + 536 MB mask restore) outside our control.
//
// LDS 33KB: k_lds[128][64]bf16 (QK) overlaid by p_lds[64][128]bf16 (PV);
// vt_lds[64][128]bf16; cnt[64] int. Swizzle byte^=(row&7)<<4 gives the uniform
// 8-lanes-per-16B-slot optimum for wave64 ds_read_b128.
// Mask tile loads straight into the MFMA C-init; Q is pre-scaled by 0.125
// (exact pow2) during bf16 convert -> softmax reads acc raw.
// Global-attn part == out[:, :G] += v[:, :G] (softmax rows sum to 1; gv has no
// s index; G == BS). Random part == out[:, ridx] += mult * v[ridx] (rowsum==1)
// -> both fused into the epilogue via per-block multiplicity counts.
__global__ __launch_bounds__(256, 4) void bb_diag(
    const float* __restrict__ q, const float* __restrict__ k,
    const float* __restrict__ v, const float* __restrict__ mask,
    const int* __restrict__ ridx, float* __restrict__ out)
{
    __shared__ __align__(16) uint8_t smem[33024];
    uint8_t* const k_lds  = smem;          // 16KB, QK phase
    uint8_t* const p_lds  = smem;          // 16KB, PV phase (overlays k_lds)
    uint8_t* const vt_lds = smem + 16384;  // 16KB
    int* const cnt = (int*)(smem + 32768); // 64 ints

    const int tid  = (int)threadIdx.x;
    const int w    = tid >> 6;     // wave 0..3
    const int lane = tid & 63;
    const int g    = lane >> 4;    // lane group 0..3
    const int c    = lane & 15;

    const int blk  = (int)blockIdx.x;
    const int half = blk >> 9;         // twins (half 0/1) are 512 apart ->
    const int rest = blk & 511;        // same XCD -> shared K/V tile hits L2
    const int h = rest & 15;
    const int n = (rest >> 4) & 15;
    const int b = rest >> 8;

    const int RS = H_ * D_;  // 1024 floats between consecutive seq rows
    const size_t base = ((size_t)((b * S_ + n * BS_) * H_ + h)) * D_;
    const float* __restrict__ qg = q + base;
    const float* __restrict__ kg = k + base;
    const float* __restrict__ vg = v + base;
    float* __restrict__ og = out + base;

    if (tid < 64) cnt[tid] = 0;

    // ---- stage K (row-major bf16) and V^T (d-major bf16), swizzled ----
    #pragma unroll
    for (int it = 0; it < 8; ++it) {
        int i   = it * 256 + tid;    // 2048 f32x4 tiles of 128x64
        int row = i >> 4;
        int c4  = i & 15;
        f32x4 kv = *(const f32x4*)(kg + (size_t)row * RS + c4 * 4);
        bf16x4 kb;
        kb[0] = (__bf16)kv[0]; kb[1] = (__bf16)kv[1];
        kb[2] = (__bf16)kv[2]; kb[3] = (__bf16)kv[3];
        uint32_t ka = ((uint32_t)(row * 128 + c4 * 8)) ^ ((row & 7) << 4);
        *(bf16x4*)(k_lds + ka) = kb;

        f32x4 vv = *(const f32x4*)(vg + (size_t)row * RS + c4 * 4);
        #pragma unroll
        for (int jj = 0; jj < 4; ++jj) {
            int j = (jj + c4) & 3;   // rotate to spread write banks
            int d = c4 * 4 + j;
            uint32_t va = ((uint32_t)(d * 256 + row * 2)) ^ ((d & 7) << 4);
            float vf = (j == 0) ? vv[0] : (j == 1) ? vv[1] : (j == 2) ? vv[2] : vv[3];
            *(__bf16*)(vt_lds + va) = (__bf16)vf;
        }
    }

    // ---- prefetch Q fragments, pre-scaled by SCALE=0.125 (exact pow2) ----
    bf16x8 qf[2];
    {
        int row_l = w * 16 + c;
        const float* qrow = qg + (size_t)(half * 64 + row_l) * RS;
        #pragma unroll
        for (int ks = 0; ks < 2; ++ks) {
            f32x4 x0 = *(const f32x4*)(qrow + ks * 32 + g * 8);
            f32x4 x1 = *(const f32x4*)(qrow + ks * 32 + g * 8 + 4);
            union { bf16x8 v8; __bf16 e[8]; } cv;
            #pragma unroll
            for (int j = 0; j < 4; ++j) {
                cv.e[j]     = (__bf16)(0.125f * x0[j]);
                cv.e[4 + j] = (__bf16)(0.125f * x1[j]);
            }
            qf[ks] = cv.v8;
        }
    }

    // ---- mask tile -> MFMA C-init (loads overlap the staging latency) ----
    f32x4 acc[8];
    {
        const float* mb = mask + ((size_t)(b * H_ + h) * S_ + n * BS_ + half * 64 + w * 16) * S_
                               + (size_t)(n * BS_);
        #pragma unroll
        for (int j = 0; j < 4; ++j) {
            const float* mrow = mb + (size_t)(g * 4 + j) * S_;
            #pragma unroll
            for (int nt = 0; nt < 8; ++nt) acc[nt][j] = mrow[nt * 16 + c];
        }
    }
    __syncthreads();

    // rand-index multiplicities for this block's 64 rows
    if (tid < 64) {
        int s = ridx[tid];
        int lo = n * BS_ + half * 64;
        if (s >= lo && s < lo + 64) atomicAdd(&cnt[s - lo], 1);
    }

    // ---- QK^T: scores[16 rows][128 cols] per wave, acc starts as mask ----
    #pragma unroll
    for (int ks = 0; ks < 2; ++ks) {
        #pragma unroll
        for (int nt = 0; nt < 8; ++nt) {
            int krow = nt * 16 + c;
            uint32_t ka = ((uint32_t)(krow * 128 + ks * 64 + g * 16)) ^ ((krow & 7) << 4);
            bf16x8 bfr = *(const bf16x8*)(k_lds + ka);
            acc[nt] = __builtin_amdgcn_mfma_f32_16x16x32_bf16(qf[ks], bfr, acc[nt], 0, 0, 0);
        }
    }
    __syncthreads();  // K-LDS reads complete before P overlays the region

    // ---- softmax (row in registers), write P (bf16) ----
    float rcp_s[4];
    #pragma unroll
    for (int j = 0; j < 4; ++j) {
        int row = w * 16 + g * 4 + j;   // local q-row 0..63 (D-layout)
        float mx = -1e30f;
        #pragma unroll
        for (int nt = 0; nt < 8; ++nt) mx = fmaxf(mx, acc[nt][j]);
        #pragma unroll
        for (int t = 1; t < 16; t <<= 1) mx = fmaxf(mx, __shfl_xor(mx, t));
        float sum = 0.f;
        #pragma unroll
        for (int nt = 0; nt < 8; ++nt) {
            float p = __expf(acc[nt][j] - mx);
            sum += p;
            uint32_t pa = ((uint32_t)(row * 256 + (nt * 16 + c) * 2)) ^ ((row & 7) << 4);
            *(__bf16*)(p_lds + pa) = (__bf16)p;
        }
        #pragma unroll
        for (int t = 1; t < 16; t <<= 1) sum += __shfl_xor(sum, t);
        rcp_s[j] = 1.0f / sum;
    }
    __syncthreads();

    // ---- PV: out[16 rows][64 d] per wave ----
    f32x4 acc2[4];
    #pragma unroll
    for (int nt = 0; nt < 4; ++nt) acc2[nt] = f32x4{0.f, 0.f, 0.f, 0.f};
    #pragma unroll
    for (int kk = 0; kk < 4; ++kk) {
        int prow = w * 16 + c;
        uint32_t pa = ((uint32_t)(prow * 256 + kk * 64 + g * 16)) ^ ((prow & 7) << 4);
        bf16x8 af = *(const bf16x8*)(p_lds + pa);
        #pragma unroll
        for (int nt = 0; nt < 4; ++nt) {
            int drow = nt * 16 + c;
            uint32_t va = ((uint32_t)(drow * 256 + kk * 64 + g * 16)) ^ ((drow & 7) << 4);
            bf16x8 bfr = *(const bf16x8*)(vt_lds + va);
            acc2[nt] = __builtin_amdgcn_mfma_f32_16x16x32_bf16(af, bfr, acc2[nt], 0, 0, 0);
        }
    }

    // ---- epilogue: normalize; fuse global-attn (+v, n==0) and rand (+mult*v)
    #pragma unroll
    for (int j = 0; j < 4; ++j) {
        int r_l = w * 16 + g * 4 + j;      // local row 0..63
        int r_t = half * 64 + r_l;         // row within the 128-row tile
        float rc = rcp_s[j];
        float coef = (float)(cnt[r_l] + ((n == 0) ? 1 : 0));
        #pragma unroll
        for (int nt = 0; nt < 4; ++nt) {
            int col = nt * 16 + c;
            float val = acc2[nt][j] * rc;
            if (coef != 0.f) val += coef * vg[(size_t)r_t * RS + col];
            og[(size_t)r_t * RS + col] = val;
        }
    }
}

extern "C" void kernel_launch(void* const* d_in, const int* in_sizes, int n_in,
                              void* d_out, int out_size, void* d_ws, size_t ws_size,
                              hipStream_t stream) {
    const float* q    = (const float*)d_in[0];
    const float* k    = (const float*)d_in[1];
    const float* v    = (const float*)d_in[2];
    const float* mask = (const float*)d_in[3];
    const int*   ridx = (const int*)d_in[4];
    float* out = (float*)d_out;

    bb_diag<<<dim3(B_ * NB_ * H_ * 2), dim3(256), 0, stream>>>(q, k, v, mask, ridx, out);
}